// Round 2
// baseline (828.783 us; speedup 1.0000x reference)
//
#include <hip/hip_runtime.h>
#include <hip/hip_bf16.h>

// GAT 2-layer, MI355X. fp32 inputs. Split-bf16 MFMA GEMM1 (exact logit path),
// CSR-by-dst aggregation with one wave per destination node.
// R5: gemm1 was latency-bound (MfmaUtil 4.7%, VALUBusy 6.5%, VGPR=40, 161us vs
// ~35us memory roofline): per-lane fragment-order A loads = 16-line gathers at
// HBM latency, ~1 iter in flight. Rewritten: double-buffered LDS A-tile
// [2][64][68] (pad 68 -> minimal-conflict ds_read_b128), coalesced reg-staged
// global->LDS with next-chunk loads issued before current-chunk MFMA. alpha1
// fused into gemm1 epilogue via LDS C-tile (drops h1f 25.6MB write + 25.6MB
// re-read + one dispatch); h1b emitted as coalesced short8 stores. Numerics
// identical (same split, same MFMA and fmaf order). CSR bucket build from R4.

typedef __attribute__((ext_vector_type(8))) short short8;
typedef __attribute__((ext_vector_type(4))) short short4v;
typedef __attribute__((ext_vector_type(4))) float float4v;

#define NEG_SLOPE 0.2f

static __device__ __forceinline__ short f2bf(float v){
    union { float f; unsigned u; } x; x.f = v;
    unsigned r = x.u + 0x7fffu + ((x.u >> 16) & 1u);   // RNE
    return (short)(r >> 16);
}
static __device__ __forceinline__ float bf2f(short s){
    union { unsigned u; float f; } x; x.u = ((unsigned)(unsigned short)s) << 16;
    return x.f;
}

// ---------- W1 pack: fp32 [512][64] -> bf16 hi/lo, transposed [64][512] ----------
__global__ void pack_w1(const float* __restrict__ W1, short* __restrict__ Whi, short* __restrict__ Wlo){
    int i = blockIdx.x*blockDim.x + threadIdx.x;       // 64*512
    if (i >= 64*512) return;
    int n = i >> 9, k = i & 511;
    float w = W1[k*64 + n];
    short h = f2bf(w);
    Whi[i] = h;
    Wlo[i] = f2bf(w - bf2f(h));
}

// ---------- edge_index int64-layout probe: all odd words zero => int64 ----------
__global__ void detect_i64(const int* __restrict__ ei, int* __restrict__ flag){
    __shared__ int any;
    if (threadIdx.x == 0) any = 0;
    __syncthreads();
    if (ei[2*threadIdx.x + 1] != 0) atomicAdd(&any, 1);
    __syncthreads();
    if (threadIdx.x == 0) flag[0] = (any == 0) ? 1 : 0;   // 1 => int64 layout
}

// ---------- layer-1 GEMM: h1 = x @ W1, split-bf16 MFMA; fused alpha1 ----------
// Block: 256 thr = 4 waves, 64 rows. LDS: A dbuf [2][64][68] fp32 (34.8KB ->
// 4 blocks/CU). Chunk BK=64: each thread stages 4 float4 coalesced.
__global__ __launch_bounds__(256, 4) void gemm1(const float* __restrict__ x,
        const short* __restrict__ Whi, const short* __restrict__ Wlo,
        const float* __restrict__ aS1, const float* __restrict__ aD1,
        short* __restrict__ h1b, float* __restrict__ as1, float* __restrict__ ad1, int N){
    __shared__ __align__(16) float As[2][64][68];
    int tid = threadIdx.x;
    int wave = tid >> 6, lane = tid & 63;
    int m = lane & 15, q = lane >> 4;
    int rowbase = blockIdx.x*64;

    // staging map: float4 id f = i*256+tid; row=f>>4 (0..63), c4=f&15
    int srow[4]; int scol[4];
    #pragma unroll
    for (int i = 0; i < 4; ++i){
        int f = i*256 + tid;
        int r = rowbase + (f >> 4);
        srow[i] = (r < N) ? r : (N-1);
        scol[i] = (f & 15) * 4;
    }

    float4 reg[4];
    #pragma unroll
    for (int i = 0; i < 4; ++i)
        reg[i] = *(const float4*)(x + (size_t)srow[i]*512 + scol[i]);
    #pragma unroll
    for (int i = 0; i < 4; ++i){
        int f = i*256 + tid;
        *(float4*)&As[0][f >> 4][scol[i]] = reg[i];
    }
    __syncthreads();

    float4v acc[4] = {};
    for (int t = 0; t < 8; ++t){
        int cur = t & 1;
        if (t < 7){
            #pragma unroll
            for (int i = 0; i < 4; ++i)
                reg[i] = *(const float4*)(x + (size_t)srow[i]*512 + (t+1)*64 + scol[i]);
        }
        const float* arow = &As[cur][wave*16 + m][0];
        #pragma unroll
        for (int ks = 0; ks < 2; ++ks){
            float v[8];
            *(float4*)&v[0] = *(const float4*)(arow + ks*32 + q*8);
            *(float4*)&v[4] = *(const float4*)(arow + ks*32 + q*8 + 4);
            short8 ahi, alo;
            #pragma unroll
            for (int j = 0; j < 8; ++j){
                union { float f; unsigned u; } tt; tt.f = v[j];
                ahi[j] = (short)(tt.u >> 16);                  // truncation split for hi
                union { unsigned u; float f; } th; th.u = tt.u & 0xffff0000u;
                alo[j] = f2bf(v[j] - th.f);
            }
            #pragma unroll
            for (int ct = 0; ct < 4; ++ct){
                const short* wb = Whi + (size_t)(ct*16+m)*512 + t*64 + ks*32 + q*8;
                const short* wl = Wlo + (size_t)(ct*16+m)*512 + t*64 + ks*32 + q*8;
                short8 bhi = *(const short8*)wb;
                short8 blo = *(const short8*)wl;
                acc[ct] = __builtin_amdgcn_mfma_f32_16x16x32_bf16(ahi, bhi, acc[ct], 0, 0, 0);
                acc[ct] = __builtin_amdgcn_mfma_f32_16x16x32_bf16(ahi, blo, acc[ct], 0, 0, 0);
                acc[ct] = __builtin_amdgcn_mfma_f32_16x16x32_bf16(alo, bhi, acc[ct], 0, 0, 0);
            }
        }
        if (t < 7){
            #pragma unroll
            for (int i = 0; i < 4; ++i){
                int f = i*256 + tid;
                *(float4*)&As[t & 1 ? 0 : 1][f >> 4][scol[i]] = reg[i];
            }
            __syncthreads();
        }
    }

    // epilogue: park acc in As[0] slice (final compute read As[1]; As[0] reads
    // all completed at iter-6 barrier; each wave touches only its own slice)
    float* cw = &As[0][0][0] + wave*(16*68);
    #pragma unroll
    for (int ct = 0; ct < 4; ++ct)
        #pragma unroll
        for (int r = 0; r < 4; ++r)
            cw[(q*4+r)*68 + ct*16 + m] = acc[ct][r];   // C/D: col=lane&15, row=quad*4+reg

    int row_l = lane >> 2;
    int cseg  = (lane & 3) * 16;
    int gr = rowbase + wave*16 + row_l;
    float vals[16];
    #pragma unroll
    for (int i = 0; i < 4; ++i)
        *(float4*)&vals[i*4] = *(const float4*)&cw[row_l*68 + cseg + i*4];
    if (gr < N){
        short8 o0, o1;
        #pragma unroll
        for (int j = 0; j < 8; ++j){ o0[j] = f2bf(vals[j]); o1[j] = f2bf(vals[8+j]); }
        *(short8*)&h1b[(size_t)gr*64 + cseg]     = o0;
        *(short8*)&h1b[(size_t)gr*64 + cseg + 8] = o1;
        int h0 = (lane & 3) * 2;
        float s0 = 0.f, d0 = 0.f, s1 = 0.f, d1 = 0.f;
        #pragma unroll
        for (int c = 0; c < 8; ++c){
            s0 = fmaf(vals[c],   aS1[h0*8+c],     s0);
            d0 = fmaf(vals[c],   aD1[h0*8+c],     d0);
            s1 = fmaf(vals[8+c], aS1[(h0+1)*8+c], s1);
            d1 = fmaf(vals[8+c], aD1[(h0+1)*8+c], d1);
        }
        float2 sv; sv.x = s0; sv.y = s1;
        float2 dv; dv.x = d0; dv.y = d1;
        *(float2*)&as1[(size_t)gr*8 + h0] = sv;
        *(float2*)&ad1[(size_t)gr*8 + h0] = dv;
    }
}

// ---------- CSR build via bucket sort (bucket = dst>>8, 256 nodes/bucket) ----------
__global__ __launch_bounds__(256) void bucket_hist(const int* __restrict__ ei,
        const int* __restrict__ flag, int* __restrict__ bhist, int E, int Etot, int K){
    extern __shared__ int hist[];                          // K ints
    for (int i = threadIdx.x; i < K; i += 256) hist[i] = 0;
    __syncthreads();
    int f = flag[0];
    int e0 = blockIdx.x*8192, e1 = min(e0 + 8192, Etot);
    for (int e = e0 + threadIdx.x; e < e1; e += 256){
        int dst = (e < E) ? ei[((size_t)(E + e)) << f] : (e - E);
        atomicAdd(&hist[dst >> 8], 1);
    }
    __syncthreads();
    for (int i = threadIdx.x; i < K; i += 256)
        if (hist[i]) atomicAdd(&bhist[i], hist[i]);
}

__global__ __launch_bounds__(1024) void bucket_scan(const int* __restrict__ bhist,
        int* __restrict__ bbase, int* __restrict__ bcursor, int K){
    __shared__ int s[1024];
    int t = threadIdx.x;
    int v = (t < K) ? bhist[t] : 0;
    s[t] = v; __syncthreads();
    for (int off = 1; off < 1024; off <<= 1){
        int x = (t >= off) ? s[t-off] : 0;
        __syncthreads();
        s[t] += x;
        __syncthreads();
    }
    if (t < K){ int excl = s[t] - v; bbase[t] = excl; bcursor[t] = excl; }
    if (t == K) bbase[K] = s[t];                           // total = Etot
}

__global__ __launch_bounds__(256) void bucket_place(const int* __restrict__ ei,
        const int* __restrict__ flag, int* __restrict__ bcursor,
        int* __restrict__ staging, int E, int Etot, int K){
    extern __shared__ int sm[];                            // hist[K] + base[K]
    int* hist = sm;
    int* base = sm + K;
    for (int i = threadIdx.x; i < K; i += 256) hist[i] = 0;
    __syncthreads();
    int f = flag[0];
    int e0 = blockIdx.x*8192, e1 = min(e0 + 8192, Etot);
    for (int e = e0 + threadIdx.x; e < e1; e += 256){
        int dst = (e < E) ? ei[((size_t)(E + e)) << f] : (e - E);
        atomicAdd(&hist[dst >> 8], 1);
    }
    __syncthreads();
    for (int i = threadIdx.x; i < K; i += 256){
        int c = hist[i];
        base[i] = c ? atomicAdd(&bcursor[i], c) : 0;
        hist[i] = 0;                                       // reuse as running cursor
    }
    __syncthreads();
    for (int e = e0 + threadIdx.x; e < e1; e += 256){
        int src, dst;
        if (e < E){ src = ei[((size_t)e) << f]; dst = ei[((size_t)(E + e)) << f]; }
        else      { src = dst = e - E; }
        int k = dst >> 8;
        int r = atomicAdd(&hist[k], 1);
        staging[base[k] + r] = (src << 8) | (dst & 255);   // src < 2^24 assumed
    }
}

__global__ __launch_bounds__(256) void bucket_csr(const int* __restrict__ staging,
        const int* __restrict__ bbase, int* __restrict__ offs, int* __restrict__ deg,
        int* __restrict__ csr, int N, int K){
    __shared__ int dcnt[256], sc[256], cur[256];
    int k = blockIdx.x, t = threadIdx.x;
    dcnt[t] = 0;
    __syncthreads();
    int s0 = bbase[k], s1 = bbase[k+1];
    for (int i = s0 + t; i < s1; i += 256)
        atomicAdd(&dcnt[staging[i] & 255], 1);
    __syncthreads();
    int v = dcnt[t];
    sc[t] = v; __syncthreads();
    for (int off = 1; off < 256; off <<= 1){
        int x = (t >= off) ? sc[t-off] : 0;
        __syncthreads();
        sc[t] += x;
        __syncthreads();
    }
    int excl = sc[t] - v;
    int node = (k << 8) + t;
    if (node < N){ offs[node] = s0 + excl; deg[node] = v; }
    cur[t] = excl;
    __syncthreads();
    for (int i = s0 + t; i < s1; i += 256){
        int ent = staging[i];
        int p = atomicAdd(&cur[ent & 255], 1);
        csr[s0 + p] = ent >> 8;
    }
}

// ---------- layer-1 aggregate: wave/dst, 4x pipelined, bf16 gather ----------
__global__ __launch_bounds__(256) void agg1(const short* __restrict__ h1b,
        const float* __restrict__ as1, const float* __restrict__ ad1,
        const int* __restrict__ offs, const int* __restrict__ deg, const int* __restrict__ csr,
        const float* __restrict__ b1, short* __restrict__ x1b, int N){
    int w = blockIdx.x*4 + (threadIdx.x >> 6);
    if (w >= N) return;
    int lane = threadIdx.x & 63, h = lane >> 3;
    int s0 = offs[w], d = deg[w];
    float ad = ad1[w*8 + h];
    float l = 0.f, acc = 0.f;
    int i = 0;
    for (; i + 4 <= d; i += 4){
        int sa = csr[s0+i], sb = csr[s0+i+1], sc = csr[s0+i+2], sd = csr[s0+i+3];
        float ea = as1[sa*8+h], eb = as1[sb*8+h], ec = as1[sc*8+h], ed = as1[sd*8+h];
        float va = bf2f(h1b[(size_t)sa*64 + lane]);
        float vb = bf2f(h1b[(size_t)sb*64 + lane]);
        float vc = bf2f(h1b[(size_t)sc*64 + lane]);
        float vd = bf2f(h1b[(size_t)sd*64 + lane]);
        ea += ad; ea = (ea > 0.f) ? ea : NEG_SLOPE*ea; float pa = __expf(ea);
        eb += ad; eb = (eb > 0.f) ? eb : NEG_SLOPE*eb; float pb = __expf(eb);
        ec += ad; ec = (ec > 0.f) ? ec : NEG_SLOPE*ec; float pc = __expf(ec);
        ed += ad; ed = (ed > 0.f) ? ed : NEG_SLOPE*ed; float pd = __expf(ed);
        l += (pa + pb) + (pc + pd);
        acc = fmaf(pa, va, acc); acc = fmaf(pb, vb, acc);
        acc = fmaf(pc, vc, acc); acc = fmaf(pd, vd, acc);
    }
    for (; i < d; ++i){
        int s = csr[s0 + i];
        float e = as1[s*8 + h] + ad;
        e = (e > 0.f) ? e : NEG_SLOPE*e;
        float p = __expf(e);
        l += p;
        acc = fmaf(p, bf2f(h1b[(size_t)s*64 + lane]), acc);
    }
    float o = acc/(l + 1e-16f) + b1[lane];
    o = (o > 0.f) ? o : (__expf(o) - 1.f);                  // ELU
    x1b[(size_t)w*64 + lane] = f2bf(o);
}

// ---------- layer-2 GEMM fused with alpha2: wave/node; fp32 logit path ----------
__global__ __launch_bounds__(256) void gemm2a(const short* __restrict__ x1b,
        const float* __restrict__ W2, const float* __restrict__ aS2, const float* __restrict__ aD2,
        short* __restrict__ h2b, float* __restrict__ as2, float* __restrict__ ad2, int N){
    __shared__ float w2s[64*40];                            // 10,240 B
    __shared__ float xs[4][64];
    int tid = threadIdx.x;
    for (int i = tid; i < 64*40; i += 256) w2s[i] = W2[i];  // W2 [64][40] row-major
    int wv = tid >> 6, lane = tid & 63;
    int n = blockIdx.x*4 + wv;
    bool valid = n < N;
    if (valid && lane < 16){
        short4v xv = *(const short4v*)&x1b[(size_t)n*64 + lane*4];
        xs[wv][lane*4+0] = bf2f(xv[0]);
        xs[wv][lane*4+1] = bf2f(xv[1]);
        xs[wv][lane*4+2] = bf2f(xv[2]);
        xs[wv][lane*4+3] = bf2f(xv[3]);
    }
    __syncthreads();
    int c = (lane < 40) ? lane : 39;
    float acc = 0.f;
    #pragma unroll 8
    for (int k = 0; k < 64; ++k)
        acc = fmaf(xs[wv][k], w2s[k*40 + c], acc);
    float s = (lane < 40) ? acc * aS2[lane] : 0.f;
    float d = (lane < 40) ? acc * aD2[lane] : 0.f;
    #pragma unroll
    for (int off = 32; off > 0; off >>= 1){ s += __shfl_down(s, off, 64); d += __shfl_down(d, off, 64); }
    if (valid){
        if (lane < 40) h2b[(size_t)n*40 + lane] = f2bf(acc);
        if (lane == 0){ as2[n] = s; ad2[n] = d; }
    }
}

// ---------- layer-2 aggregate: wave/dst, 4x pipelined, bf16 gather ----------
__global__ __launch_bounds__(256) void agg2(const short* __restrict__ h2b,
        const float* __restrict__ as2, const float* __restrict__ ad2,
        const int* __restrict__ offs, const int* __restrict__ deg, const int* __restrict__ csr,
        const float* __restrict__ b2, float* __restrict__ out, int N){
    int w = blockIdx.x*4 + (threadIdx.x >> 6);
    if (w >= N) return;
    int lane = threadIdx.x & 63;
    int c = (lane < 40) ? lane : 0;                          // clamp: in-bounds loads
    int s0 = offs[w], d = deg[w];
    float ad = ad2[w];
    float l = 0.f, acc = 0.f;
    int i = 0;
    for (; i + 4 <= d; i += 4){
        int sa = csr[s0+i], sb = csr[s0+i+1], sc = csr[s0+i+2], sd = csr[s0+i+3];
        float ea = as2[sa], eb = as2[sb], ec = as2[sc], ed = as2[sd];
        float va = bf2f(h2b[(size_t)sa*40 + c]);
        float vb = bf2f(h2b[(size_t)sb*40 + c]);
        float vc = bf2f(h2b[(size_t)sc*40 + c]);
        float vd = bf2f(h2b[(size_t)sd*40 + c]);
        ea += ad; ea = (ea > 0.f) ? ea : NEG_SLOPE*ea; float pa = __expf(ea);
        eb += ad; eb = (eb > 0.f) ? eb : NEG_SLOPE*eb; float pb = __expf(eb);
        ec += ad; ec = (ec > 0.f) ? ec : NEG_SLOPE*ec; float pc = __expf(ec);
        ed += ad; ed = (ed > 0.f) ? ed : NEG_SLOPE*ed; float pd = __expf(ed);
        l += (pa + pb) + (pc + pd);
        acc = fmaf(pa, va, acc); acc = fmaf(pb, vb, acc);
        acc = fmaf(pc, vc, acc); acc = fmaf(pd, vd, acc);
    }
    for (; i < d; ++i){
        int s = csr[s0 + i];
        float e = as2[s] + ad;
        e = (e > 0.f) ? e : NEG_SLOPE*e;
        float p = __expf(e);
        l += p;
        acc = fmaf(p, bf2f(h2b[(size_t)s*40 + c]), acc);
    }
    if (lane < 40) out[(size_t)w*40 + lane] = acc/(l + 1e-16f) + b2[lane];
}

extern "C" void kernel_launch(void* const* d_in, const int* in_sizes, int n_in,
                              void* d_out, int out_size, void* d_ws, size_t ws_size,
                              hipStream_t stream) {
    const float* x    = (const float*)d_in[0];
    const int*   ei   = (const int*)d_in[1];
    const float* W1   = (const float*)d_in[2];
    const float* aS1  = (const float*)d_in[3];
    const float* aD1  = (const float*)d_in[4];
    const float* b1   = (const float*)d_in[5];
    const float* W2   = (const float*)d_in[6];
    const float* aS2  = (const float*)d_in[7];
    const float* aD2  = (const float*)d_in[8];
    const float* b2   = (const float*)d_in[9];
    float* out = (float*)d_out;

    const int N    = in_sizes[0] / 512;
    const int E    = in_sizes[1] / 2;
    const int Etot = E + N;
    const int K    = (N + 255) >> 8;          // buckets of 256 dst nodes
    const int nAB  = (Etot + 8191) / 8192;    // edge chunks for hist/place

    // workspace carve (256B aligned), ~68 MB total
    char* p = (char*)d_ws;
    auto carve = [&](size_t bytes)->char*{ char* q = p; p += ((bytes + 255) & ~(size_t)255); return q; };
    short* h1b   = (short*)carve((size_t)N*64*2);
    short* x1b   = (short*)carve((size_t)N*64*2);
    short* h2b   = (short*)carve((size_t)N*40*2);
    float* as1   = (float*)carve((size_t)N*8*4);
    float* ad1   = (float*)carve((size_t)N*8*4);
    float* as2   = (float*)carve((size_t)N*4);
    float* ad2   = (float*)carve((size_t)N*4);
    int*   deg   = (int*)carve((size_t)N*4);
    int*   offs  = (int*)carve((size_t)N*4);
    int*   bhist = (int*)carve((size_t)(K+1)*4);
    int*   bbase = (int*)carve((size_t)(K+1)*4);
    int*   bcursor=(int*)carve((size_t)(K+1)*4);
    int*   flag  = (int*)carve(256);
    short* Whi   = (short*)carve(64*512*2);
    short* Wlo   = (short*)carve(64*512*2);
    int*   csr   = (int*)carve((size_t)Etot*4);
    int*   staging = (int*)carve((size_t)Etot*4);

    hipMemsetAsync(bhist, 0, (size_t)K*4, stream);

    detect_i64<<<1, 1024, 0, stream>>>(ei, flag);
    pack_w1<<<(64*512 + 255)/256, 256, 0, stream>>>(W1, Whi, Wlo);

    // CSR build: bucket sort, no per-edge global atomics, no random scatter.
    bucket_hist <<<nAB, 256, (size_t)K*4,   stream>>>(ei, flag, bhist, E, Etot, K);
    bucket_scan <<<1, 1024, 0,              stream>>>(bhist, bbase, bcursor, K);
    bucket_place<<<nAB, 256, (size_t)2*K*4, stream>>>(ei, flag, bcursor, staging, E, Etot, K);
    bucket_csr  <<<K, 256, 0,               stream>>>(staging, bbase, offs, deg, csr, N, K);

    gemm1 <<<(N + 63)/64, 256, 0, stream>>>(x, Whi, Wlo, aS1, aD1, h1b, as1, ad1, N);

    agg1  <<<(N + 3)/4,  256, 0, stream>>>(h1b, as1, ad1, offs, deg, csr, b1, x1b, N);
    gemm2a<<<(N + 3)/4,  256, 0, stream>>>(x1b, W2, aS2, aD2, h2b, as2, ad2, N);
    agg2  <<<(N + 3)/4,  256, 0, stream>>>(h2b, as2, ad2, offs, deg, csr, b2, out, N);
}

// Round 3
// 783.130 us; speedup vs baseline: 1.0583x; 1.0583x over previous
//
#include <hip/hip_runtime.h>
#include <hip/hip_bf16.h>

// GAT 2-layer, MI355X. fp32 inputs. Split-bf16 MFMA GEMM1 (exact logit path),
// CSR-by-dst aggregation with one wave per destination node.
// R6: gemm1 was STILL latency-bound after R5's A-side LDS staging (179us,
// MfmaUtil 4.2%, VALUBusy 6.5%) because the B loads (Whi/Wlo) were 16-line
// gathers: lane stride 1KB = (ct*16+m)*512 shorts. ~8K line-transactions per
// block vs ~1K cy of MFMA -> VMEM-issue bound. Fix: pack_w1 now emits B in
// MFMA-fragment order (((t*2+ks)*4+ct)*64+lane)*short8 so every inner-loop B
// load is one coalesced 1KB wave load from L2. Same values, same RNE split,
// same MFMA order => bit-identical. A staging + fused alpha1 epilogue from R5;
// CSR bucket build from R4.

typedef __attribute__((ext_vector_type(8))) short short8;
typedef __attribute__((ext_vector_type(4))) short short4v;
typedef __attribute__((ext_vector_type(4))) float float4v;

#define NEG_SLOPE 0.2f

static __device__ __forceinline__ short f2bf(float v){
    union { float f; unsigned u; } x; x.f = v;
    unsigned r = x.u + 0x7fffu + ((x.u >> 16) & 1u);   // RNE
    return (short)(r >> 16);
}
static __device__ __forceinline__ float bf2f(short s){
    union { unsigned u; float f; } x; x.u = ((unsigned)(unsigned short)s) << 16;
    return x.f;
}

// ---------- W1 pack: fp32 -> bf16 hi/lo in MFMA-fragment order ----------
// Fragment (t,ks,ct,lane) at short8 index ((t*2+ks)*4+ct)*64+lane, lane=q*16+m:
// element j maps to W1[k][n], n=ct*16+m, k=t*64+ks*32+q*8+j.
__global__ void pack_w1(const float* __restrict__ W1, short* __restrict__ Bhi, short* __restrict__ Blo){
    int idx = blockIdx.x*blockDim.x + threadIdx.x;     // 64*512
    if (idx >= 64*512) return;
    int j    = idx & 7;
    int lane = (idx >> 3) & 63;
    int ct   = (idx >> 9) & 3;
    int tks  = idx >> 11;                              // 0..15
    int ks = tks & 1, t = tks >> 1;
    int m = lane & 15, q = lane >> 4;
    int n = ct*16 + m;
    int k = t*64 + ks*32 + q*8 + j;
    float w = W1[k*64 + n];
    short h = f2bf(w);
    Bhi[idx] = h;
    Blo[idx] = f2bf(w - bf2f(h));
}

// ---------- edge_index int64-layout probe: all odd words zero => int64 ----------
__global__ void detect_i64(const int* __restrict__ ei, int* __restrict__ flag){
    __shared__ int any;
    if (threadIdx.x == 0) any = 0;
    __syncthreads();
    if (ei[2*threadIdx.x + 1] != 0) atomicAdd(&any, 1);
    __syncthreads();
    if (threadIdx.x == 0) flag[0] = (any == 0) ? 1 : 0;   // 1 => int64 layout
}

// ---------- layer-1 GEMM: h1 = x @ W1, split-bf16 MFMA; fused alpha1 ----------
// Block: 256 thr = 4 waves, 64 rows. LDS: A dbuf [2][64][68] fp32. B loads are
// coalesced fragment-order short8s (L2-resident, 128KB total).
__global__ __launch_bounds__(256, 4) void gemm1(const float* __restrict__ x,
        const short* __restrict__ Bhi, const short* __restrict__ Blo,
        const float* __restrict__ aS1, const float* __restrict__ aD1,
        short* __restrict__ h1b, float* __restrict__ as1, float* __restrict__ ad1, int N){
    __shared__ __align__(16) float As[2][64][68];
    int tid = threadIdx.x;
    int wave = tid >> 6, lane = tid & 63;
    int m = lane & 15, q = lane >> 4;
    int rowbase = blockIdx.x*64;

    const short8* Bh = (const short8*)Bhi;
    const short8* Bl = (const short8*)Blo;

    // staging map: float4 id f = i*256+tid; row=f>>4 (0..63), c4=f&15
    int srow[4]; int scol[4];
    #pragma unroll
    for (int i = 0; i < 4; ++i){
        int f = i*256 + tid;
        int r = rowbase + (f >> 4);
        srow[i] = (r < N) ? r : (N-1);
        scol[i] = (f & 15) * 4;
    }

    float4 reg[4];
    #pragma unroll
    for (int i = 0; i < 4; ++i)
        reg[i] = *(const float4*)(x + (size_t)srow[i]*512 + scol[i]);
    #pragma unroll
    for (int i = 0; i < 4; ++i){
        int f = i*256 + tid;
        *(float4*)&As[0][f >> 4][scol[i]] = reg[i];
    }
    __syncthreads();

    float4v acc[4] = {};
    for (int t = 0; t < 8; ++t){
        int cur = t & 1;
        if (t < 7){
            #pragma unroll
            for (int i = 0; i < 4; ++i)
                reg[i] = *(const float4*)(x + (size_t)srow[i]*512 + (t+1)*64 + scol[i]);
        }
        const float* arow = &As[cur][wave*16 + m][0];
        #pragma unroll
        for (int ks = 0; ks < 2; ++ks){
            float v[8];
            *(float4*)&v[0] = *(const float4*)(arow + ks*32 + q*8);
            *(float4*)&v[4] = *(const float4*)(arow + ks*32 + q*8 + 4);
            short8 ahi, alo;
            #pragma unroll
            for (int j = 0; j < 8; ++j){
                union { float f; unsigned u; } tt; tt.f = v[j];
                ahi[j] = (short)(tt.u >> 16);                  // truncation split for hi
                union { unsigned u; float f; } th; th.u = tt.u & 0xffff0000u;
                alo[j] = f2bf(v[j] - th.f);
            }
            int fb = ((t*2 + ks)*4)*64 + lane;                 // fragment base (+ct*64)
            #pragma unroll
            for (int ct = 0; ct < 4; ++ct){
                short8 bhi = Bh[fb + ct*64];
                short8 blo = Bl[fb + ct*64];
                acc[ct] = __builtin_amdgcn_mfma_f32_16x16x32_bf16(ahi, bhi, acc[ct], 0, 0, 0);
                acc[ct] = __builtin_amdgcn_mfma_f32_16x16x32_bf16(ahi, blo, acc[ct], 0, 0, 0);
                acc[ct] = __builtin_amdgcn_mfma_f32_16x16x32_bf16(alo, bhi, acc[ct], 0, 0, 0);
            }
        }
        if (t < 7){
            #pragma unroll
            for (int i = 0; i < 4; ++i){
                int f = i*256 + tid;
                *(float4*)&As[t & 1 ? 0 : 1][f >> 4][scol[i]] = reg[i];
            }
            __syncthreads();
        }
    }

    // epilogue: park acc in As[0] slice (final compute read As[1]; As[0] reads
    // all completed at iter-6 barrier; each wave touches only its own slice)
    float* cw = &As[0][0][0] + wave*(16*68);
    #pragma unroll
    for (int ct = 0; ct < 4; ++ct)
        #pragma unroll
        for (int r = 0; r < 4; ++r)
            cw[(q*4+r)*68 + ct*16 + m] = acc[ct][r];   // C/D: col=lane&15, row=quad*4+reg

    int row_l = lane >> 2;
    int cseg  = (lane & 3) * 16;
    int gr = rowbase + wave*16 + row_l;
    float vals[16];
    #pragma unroll
    for (int i = 0; i < 4; ++i)
        *(float4*)&vals[i*4] = *(const float4*)&cw[row_l*68 + cseg + i*4];
    if (gr < N){
        short8 o0, o1;
        #pragma unroll
        for (int j = 0; j < 8; ++j){ o0[j] = f2bf(vals[j]); o1[j] = f2bf(vals[8+j]); }
        *(short8*)&h1b[(size_t)gr*64 + cseg]     = o0;
        *(short8*)&h1b[(size_t)gr*64 + cseg + 8] = o1;
        int h0 = (lane & 3) * 2;
        float s0 = 0.f, d0 = 0.f, s1 = 0.f, d1 = 0.f;
        #pragma unroll
        for (int c = 0; c < 8; ++c){
            s0 = fmaf(vals[c],   aS1[h0*8+c],     s0);
            d0 = fmaf(vals[c],   aD1[h0*8+c],     d0);
            s1 = fmaf(vals[8+c], aS1[(h0+1)*8+c], s1);
            d1 = fmaf(vals[8+c], aD1[(h0+1)*8+c], d1);
        }
        float2 sv; sv.x = s0; sv.y = s1;
        float2 dv; dv.x = d0; dv.y = d1;
        *(float2*)&as1[(size_t)gr*8 + h0] = sv;
        *(float2*)&ad1[(size_t)gr*8 + h0] = dv;
    }
}

// ---------- CSR build via bucket sort (bucket = dst>>8, 256 nodes/bucket) ----------
__global__ __launch_bounds__(256) void bucket_hist(const int* __restrict__ ei,
        const int* __restrict__ flag, int* __restrict__ bhist, int E, int Etot, int K){
    extern __shared__ int hist[];                          // K ints
    for (int i = threadIdx.x; i < K; i += 256) hist[i] = 0;
    __syncthreads();
    int f = flag[0];
    int e0 = blockIdx.x*8192, e1 = min(e0 + 8192, Etot);
    for (int e = e0 + threadIdx.x; e < e1; e += 256){
        int dst = (e < E) ? ei[((size_t)(E + e)) << f] : (e - E);
        atomicAdd(&hist[dst >> 8], 1);
    }
    __syncthreads();
    for (int i = threadIdx.x; i < K; i += 256)
        if (hist[i]) atomicAdd(&bhist[i], hist[i]);
}

__global__ __launch_bounds__(1024) void bucket_scan(const int* __restrict__ bhist,
        int* __restrict__ bbase, int* __restrict__ bcursor, int K){
    __shared__ int s[1024];
    int t = threadIdx.x;
    int v = (t < K) ? bhist[t] : 0;
    s[t] = v; __syncthreads();
    for (int off = 1; off < 1024; off <<= 1){
        int x = (t >= off) ? s[t-off] : 0;
        __syncthreads();
        s[t] += x;
        __syncthreads();
    }
    if (t < K){ int excl = s[t] - v; bbase[t] = excl; bcursor[t] = excl; }
    if (t == K) bbase[K] = s[t];                           // total = Etot
}

__global__ __launch_bounds__(256) void bucket_place(const int* __restrict__ ei,
        const int* __restrict__ flag, int* __restrict__ bcursor,
        int* __restrict__ staging, int E, int Etot, int K){
    extern __shared__ int sm[];                            // hist[K] + base[K]
    int* hist = sm;
    int* base = sm + K;
    for (int i = threadIdx.x; i < K; i += 256) hist[i] = 0;
    __syncthreads();
    int f = flag[0];
    int e0 = blockIdx.x*8192, e1 = min(e0 + 8192, Etot);
    for (int e = e0 + threadIdx.x; e < e1; e += 256){
        int dst = (e < E) ? ei[((size_t)(E + e)) << f] : (e - E);
        atomicAdd(&hist[dst >> 8], 1);
    }
    __syncthreads();
    for (int i = threadIdx.x; i < K; i += 256){
        int c = hist[i];
        base[i] = c ? atomicAdd(&bcursor[i], c) : 0;
        hist[i] = 0;                                       // reuse as running cursor
    }
    __syncthreads();
    for (int e = e0 + threadIdx.x; e < e1; e += 256){
        int src, dst;
        if (e < E){ src = ei[((size_t)e) << f]; dst = ei[((size_t)(E + e)) << f]; }
        else      { src = dst = e - E; }
        int k = dst >> 8;
        int r = atomicAdd(&hist[k], 1);
        staging[base[k] + r] = (src << 8) | (dst & 255);   // src < 2^24 assumed
    }
}

__global__ __launch_bounds__(256) void bucket_csr(const int* __restrict__ staging,
        const int* __restrict__ bbase, int* __restrict__ offs, int* __restrict__ deg,
        int* __restrict__ csr, int N, int K){
    __shared__ int dcnt[256], sc[256], cur[256];
    int k = blockIdx.x, t = threadIdx.x;
    dcnt[t] = 0;
    __syncthreads();
    int s0 = bbase[k], s1 = bbase[k+1];
    for (int i = s0 + t; i < s1; i += 256)
        atomicAdd(&dcnt[staging[i] & 255], 1);
    __syncthreads();
    int v = dcnt[t];
    sc[t] = v; __syncthreads();
    for (int off = 1; off < 256; off <<= 1){
        int x = (t >= off) ? sc[t-off] : 0;
        __syncthreads();
        sc[t] += x;
        __syncthreads();
    }
    int excl = sc[t] - v;
    int node = (k << 8) + t;
    if (node < N){ offs[node] = s0 + excl; deg[node] = v; }
    cur[t] = excl;
    __syncthreads();
    for (int i = s0 + t; i < s1; i += 256){
        int ent = staging[i];
        int p = atomicAdd(&cur[ent & 255], 1);
        csr[s0 + p] = ent >> 8;
    }
}

// ---------- layer-1 aggregate: wave/dst, 4x pipelined, bf16 gather ----------
__global__ __launch_bounds__(256) void agg1(const short* __restrict__ h1b,
        const float* __restrict__ as1, const float* __restrict__ ad1,
        const int* __restrict__ offs, const int* __restrict__ deg, const int* __restrict__ csr,
        const float* __restrict__ b1, short* __restrict__ x1b, int N){
    int w = blockIdx.x*4 + (threadIdx.x >> 6);
    if (w >= N) return;
    int lane = threadIdx.x & 63, h = lane >> 3;
    int s0 = offs[w], d = deg[w];
    float ad = ad1[w*8 + h];
    float l = 0.f, acc = 0.f;
    int i = 0;
    for (; i + 4 <= d; i += 4){
        int sa = csr[s0+i], sb = csr[s0+i+1], sc = csr[s0+i+2], sd = csr[s0+i+3];
        float ea = as1[sa*8+h], eb = as1[sb*8+h], ec = as1[sc*8+h], ed = as1[sd*8+h];
        float va = bf2f(h1b[(size_t)sa*64 + lane]);
        float vb = bf2f(h1b[(size_t)sb*64 + lane]);
        float vc = bf2f(h1b[(size_t)sc*64 + lane]);
        float vd = bf2f(h1b[(size_t)sd*64 + lane]);
        ea += ad; ea = (ea > 0.f) ? ea : NEG_SLOPE*ea; float pa = __expf(ea);
        eb += ad; eb = (eb > 0.f) ? eb : NEG_SLOPE*eb; float pb = __expf(eb);
        ec += ad; ec = (ec > 0.f) ? ec : NEG_SLOPE*ec; float pc = __expf(ec);
        ed += ad; ed = (ed > 0.f) ? ed : NEG_SLOPE*ed; float pd = __expf(ed);
        l += (pa + pb) + (pc + pd);
        acc = fmaf(pa, va, acc); acc = fmaf(pb, vb, acc);
        acc = fmaf(pc, vc, acc); acc = fmaf(pd, vd, acc);
    }
    for (; i < d; ++i){
        int s = csr[s0 + i];
        float e = as1[s*8 + h] + ad;
        e = (e > 0.f) ? e : NEG_SLOPE*e;
        float p = __expf(e);
        l += p;
        acc = fmaf(p, bf2f(h1b[(size_t)s*64 + lane]), acc);
    }
    float o = acc/(l + 1e-16f) + b1[lane];
    o = (o > 0.f) ? o : (__expf(o) - 1.f);                  // ELU
    x1b[(size_t)w*64 + lane] = f2bf(o);
}

// ---------- layer-2 GEMM fused with alpha2: wave/node; fp32 logit path ----------
__global__ __launch_bounds__(256) void gemm2a(const short* __restrict__ x1b,
        const float* __restrict__ W2, const float* __restrict__ aS2, const float* __restrict__ aD2,
        short* __restrict__ h2b, float* __restrict__ as2, float* __restrict__ ad2, int N){
    __shared__ float w2s[64*40];                            // 10,240 B
    __shared__ float xs[4][64];
    int tid = threadIdx.x;
    for (int i = tid; i < 64*40; i += 256) w2s[i] = W2[i];  // W2 [64][40] row-major
    int wv = tid >> 6, lane = tid & 63;
    int n = blockIdx.x*4 + wv;
    bool valid = n < N;
    if (valid && lane < 16){
        short4v xv = *(const short4v*)&x1b[(size_t)n*64 + lane*4];
        xs[wv][lane*4+0] = bf2f(xv[0]);
        xs[wv][lane*4+1] = bf2f(xv[1]);
        xs[wv][lane*4+2] = bf2f(xv[2]);
        xs[wv][lane*4+3] = bf2f(xv[3]);
    }
    __syncthreads();
    int c = (lane < 40) ? lane : 39;
    float acc = 0.f;
    #pragma unroll 8
    for (int k = 0; k < 64; ++k)
        acc = fmaf(xs[wv][k], w2s[k*40 + c], acc);
    float s = (lane < 40) ? acc * aS2[lane] : 0.f;
    float d = (lane < 40) ? acc * aD2[lane] : 0.f;
    #pragma unroll
    for (int off = 32; off > 0; off >>= 1){ s += __shfl_down(s, off, 64); d += __shfl_down(d, off, 64); }
    if (valid){
        if (lane < 40) h2b[(size_t)n*40 + lane] = f2bf(acc);
        if (lane == 0){ as2[n] = s; ad2[n] = d; }
    }
}

// ---------- layer-2 aggregate: wave/dst, 4x pipelined, bf16 gather ----------
__global__ __launch_bounds__(256) void agg2(const short* __restrict__ h2b,
        const float* __restrict__ as2, const float* __restrict__ ad2,
        const int* __restrict__ offs, const int* __restrict__ deg, const int* __restrict__ csr,
        const float* __restrict__ b2, float* __restrict__ out, int N){
    int w = blockIdx.x*4 + (threadIdx.x >> 6);
    if (w >= N) return;
    int lane = threadIdx.x & 63;
    int c = (lane < 40) ? lane : 0;                          // clamp: in-bounds loads
    int s0 = offs[w], d = deg[w];
    float ad = ad2[w];
    float l = 0.f, acc = 0.f;
    int i = 0;
    for (; i + 4 <= d; i += 4){
        int sa = csr[s0+i], sb = csr[s0+i+1], sc = csr[s0+i+2], sd = csr[s0+i+3];
        float ea = as2[sa], eb = as2[sb], ec = as2[sc], ed = as2[sd];
        float va = bf2f(h2b[(size_t)sa*40 + c]);
        float vb = bf2f(h2b[(size_t)sb*40 + c]);
        float vc = bf2f(h2b[(size_t)sc*40 + c]);
        float vd = bf2f(h2b[(size_t)sd*40 + c]);
        ea += ad; ea = (ea > 0.f) ? ea : NEG_SLOPE*ea; float pa = __expf(ea);
        eb += ad; eb = (eb > 0.f) ? eb : NEG_SLOPE*eb; float pb = __expf(eb);
        ec += ad; ec = (ec > 0.f) ? ec : NEG_SLOPE*ec; float pc = __expf(ec);
        ed += ad; ed = (ed > 0.f) ? ed : NEG_SLOPE*ed; float pd = __expf(ed);
        l += (pa + pb) + (pc + pd);
        acc = fmaf(pa, va, acc); acc = fmaf(pb, vb, acc);
        acc = fmaf(pc, vc, acc); acc = fmaf(pd, vd, acc);
    }
    for (; i < d; ++i){
        int s = csr[s0 + i];
        float e = as2[s] + ad;
        e = (e > 0.f) ? e : NEG_SLOPE*e;
        float p = __expf(e);
        l += p;
        acc = fmaf(p, bf2f(h2b[(size_t)s*40 + c]), acc);
    }
    if (lane < 40) out[(size_t)w*40 + lane] = acc/(l + 1e-16f) + b2[lane];
}

extern "C" void kernel_launch(void* const* d_in, const int* in_sizes, int n_in,
                              void* d_out, int out_size, void* d_ws, size_t ws_size,
                              hipStream_t stream) {
    const float* x    = (const float*)d_in[0];
    const int*   ei   = (const int*)d_in[1];
    const float* W1   = (const float*)d_in[2];
    const float* aS1  = (const float*)d_in[3];
    const float* aD1  = (const float*)d_in[4];
    const float* b1   = (const float*)d_in[5];
    const float* W2   = (const float*)d_in[6];
    const float* aS2  = (const float*)d_in[7];
    const float* aD2  = (const float*)d_in[8];
    const float* b2   = (const float*)d_in[9];
    float* out = (float*)d_out;

    const int N    = in_sizes[0] / 512;
    const int E    = in_sizes[1] / 2;
    const int Etot = E + N;
    const int K    = (N + 255) >> 8;          // buckets of 256 dst nodes
    const int nAB  = (Etot + 8191) / 8192;    // edge chunks for hist/place

    // workspace carve (256B aligned), ~68 MB total
    char* p = (char*)d_ws;
    auto carve = [&](size_t bytes)->char*{ char* q = p; p += ((bytes + 255) & ~(size_t)255); return q; };
    short* h1b   = (short*)carve((size_t)N*64*2);
    short* x1b   = (short*)carve((size_t)N*64*2);
    short* h2b   = (short*)carve((size_t)N*40*2);
    float* as1   = (float*)carve((size_t)N*8*4);
    float* ad1   = (float*)carve((size_t)N*8*4);
    float* as2   = (float*)carve((size_t)N*4);
    float* ad2   = (float*)carve((size_t)N*4);
    int*   deg   = (int*)carve((size_t)N*4);
    int*   offs  = (int*)carve((size_t)N*4);
    int*   bhist = (int*)carve((size_t)(K+1)*4);
    int*   bbase = (int*)carve((size_t)(K+1)*4);
    int*   bcursor=(int*)carve((size_t)(K+1)*4);
    int*   flag  = (int*)carve(256);
    short* Bhi   = (short*)carve(64*512*2);
    short* Blo   = (short*)carve(64*512*2);
    int*   csr   = (int*)carve((size_t)Etot*4);
    int*   staging = (int*)carve((size_t)Etot*4);

    hipMemsetAsync(bhist, 0, (size_t)K*4, stream);

    detect_i64<<<1, 1024, 0, stream>>>(ei, flag);
    pack_w1<<<(64*512 + 255)/256, 256, 0, stream>>>(W1, Bhi, Blo);

    // CSR build: bucket sort, no per-edge global atomics, no random scatter.
    bucket_hist <<<nAB, 256, (size_t)K*4,   stream>>>(ei, flag, bhist, E, Etot, K);
    bucket_scan <<<1, 1024, 0,              stream>>>(bhist, bbase, bcursor, K);
    bucket_place<<<nAB, 256, (size_t)2*K*4, stream>>>(ei, flag, bcursor, staging, E, Etot, K);
    bucket_csr  <<<K, 256, 0,               stream>>>(staging, bbase, offs, deg, csr, N, K);

    gemm1 <<<(N + 63)/64, 256, 0, stream>>>(x, Bhi, Blo, aS1, aD1, h1b, as1, ad1, N);

    agg1  <<<(N + 3)/4,  256, 0, stream>>>(h1b, as1, ad1, offs, deg, csr, b1, x1b, N);
    gemm2a<<<(N + 3)/4,  256, 0, stream>>>(x1b, W2, aS2, aD2, h2b, as2, ad2, N);
    agg2  <<<(N + 3)/4,  256, 0, stream>>>(h2b, as2, ad2, offs, deg, csr, b2, out, N);
}

// Round 6
// 696.419 us; speedup vs baseline: 1.1901x; 1.1245x over previous
//
#include <hip/hip_runtime.h>
#include <hip/hip_bf16.h>

// GAT 2-layer, MI355X. fp32 inputs. Split-bf16 MFMA GEMM1 (exact logit path),
// CSR-by-dst aggregation.
// R9 = R7 resubmit, 3rd attempt ("container failed twice" x2 = infra-level
// error; second audit found no alignment/bounds/sync/hang hazard in the diff;
// push timings showed degraded infra). Cosmetic hardening only: agg early
// returns -> if(w<N) guards.
// R7: agg1 was VALU-issue-bound (135us, VALUBusy 82%, HBM 28%): 64-lane wave
// per dst processed ONE edge/iter -> per-edge addr arith + 8x-redundant
// exp/leaky chain paid wave-wide for a 128B payload. Restructured both agg
// kernels to 16-lane groups (4 nodes/wave): each lane owns 4 features via one
// ushort4 load (all in one head, h=r>>1), logit chain 2x-redundant, one wave
// instr advances 4 edges => ~3x fewer VALU instrs/edge. Same fma/sum order =>
// bit-identical. agg2: lanes r<10 carry the 40 features. gemm1 fragment-order
// B + LDS A staging from R6; bucket CSR from R4.

typedef __attribute__((ext_vector_type(8))) short short8;
typedef __attribute__((ext_vector_type(4))) short short4v;
typedef __attribute__((ext_vector_type(4))) float float4v;

#define NEG_SLOPE 0.2f

static __device__ __forceinline__ short f2bf(float v){
    union { float f; unsigned u; } x; x.f = v;
    unsigned r = x.u + 0x7fffu + ((x.u >> 16) & 1u);   // RNE
    return (short)(r >> 16);
}
static __device__ __forceinline__ float bf2f(short s){
    union { unsigned u; float f; } x; x.u = ((unsigned)(unsigned short)s) << 16;
    return x.f;
}

// ---------- W1 pack: fp32 -> bf16 hi/lo in MFMA-fragment order ----------
// Fragment (t,ks,ct,lane) at short8 index ((t*2+ks)*4+ct)*64+lane, lane=q*16+m:
// element j maps to W1[k][n], n=ct*16+m, k=t*64+ks*32+q*8+j.
__global__ void pack_w1(const float* __restrict__ W1, short* __restrict__ Bhi, short* __restrict__ Blo){
    int idx = blockIdx.x*blockDim.x + threadIdx.x;     // 64*512
    if (idx >= 64*512) return;
    int j    = idx & 7;
    int lane = (idx >> 3) & 63;
    int ct   = (idx >> 9) & 3;
    int tks  = idx >> 11;                              // 0..15
    int ks = tks & 1, t = tks >> 1;
    int m = lane & 15, q = lane >> 4;
    int n = ct*16 + m;
    int k = t*64 + ks*32 + q*8 + j;
    float w = W1[k*64 + n];
    short h = f2bf(w);
    Bhi[idx] = h;
    Blo[idx] = f2bf(w - bf2f(h));
}

// ---------- edge_index int64-layout probe: all odd words zero => int64 ----------
__global__ void detect_i64(const int* __restrict__ ei, int* __restrict__ flag){
    __shared__ int any;
    if (threadIdx.x == 0) any = 0;
    __syncthreads();
    if (ei[2*threadIdx.x + 1] != 0) atomicAdd(&any, 1);
    __syncthreads();
    if (threadIdx.x == 0) flag[0] = (any == 0) ? 1 : 0;   // 1 => int64 layout
}

// ---------- layer-1 GEMM: h1 = x @ W1, split-bf16 MFMA; fused alpha1 ----------
__global__ __launch_bounds__(256, 4) void gemm1(const float* __restrict__ x,
        const short* __restrict__ Bhi, const short* __restrict__ Blo,
        const float* __restrict__ aS1, const float* __restrict__ aD1,
        short* __restrict__ h1b, float* __restrict__ as1, float* __restrict__ ad1, int N){
    __shared__ __align__(16) float As[2][64][68];
    int tid = threadIdx.x;
    int wave = tid >> 6, lane = tid & 63;
    int m = lane & 15, q = lane >> 4;
    int rowbase = blockIdx.x*64;

    const short8* Bh = (const short8*)Bhi;
    const short8* Bl = (const short8*)Blo;

    // staging map: float4 id f = i*256+tid; row=f>>4 (0..63), c4=f&15
    int srow[4]; int scol[4];
    #pragma unroll
    for (int i = 0; i < 4; ++i){
        int f = i*256 + tid;
        int r = rowbase + (f >> 4);
        srow[i] = (r < N) ? r : (N-1);
        scol[i] = (f & 15) * 4;
    }

    float4 reg[4];
    #pragma unroll
    for (int i = 0; i < 4; ++i)
        reg[i] = *(const float4*)(x + (size_t)srow[i]*512 + scol[i]);
    #pragma unroll
    for (int i = 0; i < 4; ++i){
        int f = i*256 + tid;
        *(float4*)&As[0][f >> 4][scol[i]] = reg[i];
    }
    __syncthreads();

    float4v acc[4] = {};
    for (int t = 0; t < 8; ++t){
        int cur = t & 1;
        if (t < 7){
            #pragma unroll
            for (int i = 0; i < 4; ++i)
                reg[i] = *(const float4*)(x + (size_t)srow[i]*512 + (t+1)*64 + scol[i]);
        }
        const float* arow = &As[cur][wave*16 + m][0];
        #pragma unroll
        for (int ks = 0; ks < 2; ++ks){
            float v[8];
            *(float4*)&v[0] = *(const float4*)(arow + ks*32 + q*8);
            *(float4*)&v[4] = *(const float4*)(arow + ks*32 + q*8 + 4);
            short8 ahi, alo;
            #pragma unroll
            for (int j = 0; j < 8; ++j){
                union { float f; unsigned u; } tt; tt.f = v[j];
                ahi[j] = (short)(tt.u >> 16);                  // truncation split for hi
                union { unsigned u; float f; } th; th.u = tt.u & 0xffff0000u;
                alo[j] = f2bf(v[j] - th.f);
            }
            int fb = ((t*2 + ks)*4)*64 + lane;                 // fragment base (+ct*64)
            #pragma unroll
            for (int ct = 0; ct < 4; ++ct){
                short8 bhi = Bh[fb + ct*64];
                short8 blo = Bl[fb + ct*64];
                acc[ct] = __builtin_amdgcn_mfma_f32_16x16x32_bf16(ahi, bhi, acc[ct], 0, 0, 0);
                acc[ct] = __builtin_amdgcn_mfma_f32_16x16x32_bf16(ahi, blo, acc[ct], 0, 0, 0);
                acc[ct] = __builtin_amdgcn_mfma_f32_16x16x32_bf16(alo, bhi, acc[ct], 0, 0, 0);
            }
        }
        if (t < 7){
            #pragma unroll
            for (int i = 0; i < 4; ++i){
                int f = i*256 + tid;
                *(float4*)&As[t & 1 ? 0 : 1][f >> 4][scol[i]] = reg[i];
            }
            __syncthreads();
        }
    }

    // epilogue: park acc in As[0] slice; coalesced h1b stores + fused alpha1
    float* cw = &As[0][0][0] + wave*(16*68);
    #pragma unroll
    for (int ct = 0; ct < 4; ++ct)
        #pragma unroll
        for (int r = 0; r < 4; ++r)
            cw[(q*4+r)*68 + ct*16 + m] = acc[ct][r];   // C/D: col=lane&15, row=quad*4+reg

    int row_l = lane >> 2;
    int cseg  = (lane & 3) * 16;
    int gr = rowbase + wave*16 + row_l;
    float vals[16];
    #pragma unroll
    for (int i = 0; i < 4; ++i)
        *(float4*)&vals[i*4] = *(const float4*)&cw[row_l*68 + cseg + i*4];
    if (gr < N){
        short8 o0, o1;
        #pragma unroll
        for (int j = 0; j < 8; ++j){ o0[j] = f2bf(vals[j]); o1[j] = f2bf(vals[8+j]); }
        *(short8*)&h1b[(size_t)gr*64 + cseg]     = o0;
        *(short8*)&h1b[(size_t)gr*64 + cseg + 8] = o1;
        int h0 = (lane & 3) * 2;
        float s0 = 0.f, d0 = 0.f, s1 = 0.f, d1 = 0.f;
        #pragma unroll
        for (int c = 0; c < 8; ++c){
            s0 = fmaf(vals[c],   aS1[h0*8+c],     s0);
            d0 = fmaf(vals[c],   aD1[h0*8+c],     d0);
            s1 = fmaf(vals[8+c], aS1[(h0+1)*8+c], s1);
            d1 = fmaf(vals[8+c], aD1[(h0+1)*8+c], d1);
        }
        float2 sv; sv.x = s0; sv.y = s1;
        float2 dv; dv.x = d0; dv.y = d1;
        *(float2*)&as1[(size_t)gr*8 + h0] = sv;
        *(float2*)&ad1[(size_t)gr*8 + h0] = dv;
    }
}

// ---------- CSR build via bucket sort (bucket = dst>>8, 256 nodes/bucket) ----------
__global__ __launch_bounds__(256) void bucket_hist(const int* __restrict__ ei,
        const int* __restrict__ flag, int* __restrict__ bhist, int E, int Etot, int K){
    extern __shared__ int hist[];                          // K ints
    for (int i = threadIdx.x; i < K; i += 256) hist[i] = 0;
    __syncthreads();
    int f = flag[0];
    int e0 = blockIdx.x*8192, e1 = min(e0 + 8192, Etot);
    for (int e = e0 + threadIdx.x; e < e1; e += 256){
        int dst = (e < E) ? ei[((size_t)(E + e)) << f] : (e - E);
        atomicAdd(&hist[dst >> 8], 1);
    }
    __syncthreads();
    for (int i = threadIdx.x; i < K; i += 256)
        if (hist[i]) atomicAdd(&bhist[i], hist[i]);
}

__global__ __launch_bounds__(1024) void bucket_scan(const int* __restrict__ bhist,
        int* __restrict__ bbase, int* __restrict__ bcursor, int K){
    __shared__ int s[1024];
    int t = threadIdx.x;
    int v = (t < K) ? bhist[t] : 0;
    s[t] = v; __syncthreads();
    for (int off = 1; off < 1024; off <<= 1){
        int x = (t >= off) ? s[t-off] : 0;
        __syncthreads();
        s[t] += x;
        __syncthreads();
    }
    if (t < K){ int excl = s[t] - v; bbase[t] = excl; bcursor[t] = excl; }
    if (t == K) bbase[K] = s[t];                           // total = Etot
}

__global__ __launch_bounds__(256) void bucket_place(const int* __restrict__ ei,
        const int* __restrict__ flag, int* __restrict__ bcursor,
        int* __restrict__ staging, int E, int Etot, int K){
    extern __shared__ int sm[];                            // hist[K] + base[K]
    int* hist = sm;
    int* base = sm + K;
    for (int i = threadIdx.x; i < K; i += 256) hist[i] = 0;
    __syncthreads();
    int f = flag[0];
    int e0 = blockIdx.x*8192, e1 = min(e0 + 8192, Etot);
    for (int e = e0 + threadIdx.x; e < e1; e += 256){
        int dst = (e < E) ? ei[((size_t)(E + e)) << f] : (e - E);
        atomicAdd(&hist[dst >> 8], 1);
    }
    __syncthreads();
    for (int i = threadIdx.x; i < K; i += 256){
        int c = hist[i];
        base[i] = c ? atomicAdd(&bcursor[i], c) : 0;
        hist[i] = 0;                                       // reuse as running cursor
    }
    __syncthreads();
    for (int e = e0 + threadIdx.x; e < e1; e += 256){
        int src, dst;
        if (e < E){ src = ei[((size_t)e) << f]; dst = ei[((size_t)(E + e)) << f]; }
        else      { src = dst = e - E; }
        int k = dst >> 8;
        int r = atomicAdd(&hist[k], 1);
        staging[base[k] + r] = (src << 8) | (dst & 255);   // src < 2^24 assumed
    }
}

__global__ __launch_bounds__(256) void bucket_csr(const int* __restrict__ staging,
        const int* __restrict__ bbase, int* __restrict__ offs, int* __restrict__ deg,
        int* __restrict__ csr, int N, int K){
    __shared__ int dcnt[256], sc[256], cur[256];
    int k = blockIdx.x, t = threadIdx.x;
    dcnt[t] = 0;
    __syncthreads();
    int s0 = bbase[k], s1 = bbase[k+1];
    for (int i = s0 + t; i < s1; i += 256)
        atomicAdd(&dcnt[staging[i] & 255], 1);
    __syncthreads();
    int v = dcnt[t];
    sc[t] = v; __syncthreads();
    for (int off = 1; off < 256; off <<= 1){
        int x = (t >= off) ? sc[t-off] : 0;
        __syncthreads();
        sc[t] += x;
        __syncthreads();
    }
    int excl = sc[t] - v;
    int node = (k << 8) + t;
    if (node < N){ offs[node] = s0 + excl; deg[node] = v; }
    cur[t] = excl;
    __syncthreads();
    for (int i = s0 + t; i < s1; i += 256){
        int ent = staging[i];
        int p = atomicAdd(&cur[ent & 255], 1);
        csr[s0 + p] = ent >> 8;
    }
}

// ---------- layer-1 aggregate: 16-lane group/dst, lane owns 4 features ----------
__global__ __launch_bounds__(256) void agg1(const short* __restrict__ h1b,
        const float* __restrict__ as1, const float* __restrict__ ad1,
        const int* __restrict__ offs, const int* __restrict__ deg, const int* __restrict__ csr,
        const float* __restrict__ b1, short* __restrict__ x1b, int N){
    int w = blockIdx.x*16 + (threadIdx.x >> 4);
    if (w < N){
        int r = threadIdx.x & 15;
        int h = r >> 1;                  // features r*4..r*4+3 all in head r>>1
        int f0 = r*4;
        int s0 = offs[w], d = deg[w];
        float ad = ad1[w*8 + h];
        float l = 0.f;
        float4v acc = {};
        int i = 0;
        for (; i + 4 <= d; i += 4){
            int sa = csr[s0+i], sb = csr[s0+i+1], sc = csr[s0+i+2], sd = csr[s0+i+3];
            float ea = as1[sa*8+h], eb = as1[sb*8+h], ec = as1[sc*8+h], ed = as1[sd*8+h];
            short4v va = *(const short4v*)&h1b[(size_t)sa*64 + f0];
            short4v vb = *(const short4v*)&h1b[(size_t)sb*64 + f0];
            short4v vc = *(const short4v*)&h1b[(size_t)sc*64 + f0];
            short4v vd = *(const short4v*)&h1b[(size_t)sd*64 + f0];
            ea += ad; ea = (ea > 0.f) ? ea : NEG_SLOPE*ea; float pa = __expf(ea);
            eb += ad; eb = (eb > 0.f) ? eb : NEG_SLOPE*eb; float pb = __expf(eb);
            ec += ad; ec = (ec > 0.f) ? ec : NEG_SLOPE*ec; float pc = __expf(ec);
            ed += ad; ed = (ed > 0.f) ? ed : NEG_SLOPE*ed; float pd = __expf(ed);
            l += (pa + pb) + (pc + pd);
            #pragma unroll
            for (int j = 0; j < 4; ++j){
                acc[j] = fmaf(pa, bf2f(va[j]), acc[j]);
                acc[j] = fmaf(pb, bf2f(vb[j]), acc[j]);
                acc[j] = fmaf(pc, bf2f(vc[j]), acc[j]);
                acc[j] = fmaf(pd, bf2f(vd[j]), acc[j]);
            }
        }
        for (; i < d; ++i){
            int s = csr[s0 + i];
            float e = as1[s*8 + h] + ad;
            e = (e > 0.f) ? e : NEG_SLOPE*e;
            float p = __expf(e);
            l += p;
            short4v v = *(const short4v*)&h1b[(size_t)s*64 + f0];
            #pragma unroll
            for (int j = 0; j < 4; ++j)
                acc[j] = fmaf(p, bf2f(v[j]), acc[j]);
        }
        short4v o;
        #pragma unroll
        for (int j = 0; j < 4; ++j){
            float ov = acc[j]/(l + 1e-16f) + b1[f0+j];
            ov = (ov > 0.f) ? ov : (__expf(ov) - 1.f);       // ELU
            o[j] = f2bf(ov);
        }
        *(short4v*)&x1b[(size_t)w*64 + f0] = o;
    }
}

// ---------- layer-2 GEMM fused with alpha2: wave/node; fp32 logit path ----------
__global__ __launch_bounds__(256) void gemm2a(const short* __restrict__ x1b,
        const float* __restrict__ W2, const float* __restrict__ aS2, const float* __restrict__ aD2,
        short* __restrict__ h2b, float* __restrict__ as2, float* __restrict__ ad2, int N){
    __shared__ float w2s[64*40];                            // 10,240 B
    __shared__ float xs[4][64];
    int tid = threadIdx.x;
    for (int i = tid; i < 64*40; i += 256) w2s[i] = W2[i];  // W2 [64][40] row-major
    int wv = tid >> 6, lane = tid & 63;
    int n = blockIdx.x*4 + wv;
    bool valid = n < N;
    if (valid && lane < 16){
        short4v xv = *(const short4v*)&x1b[(size_t)n*64 + lane*4];
        xs[wv][lane*4+0] = bf2f(xv[0]);
        xs[wv][lane*4+1] = bf2f(xv[1]);
        xs[wv][lane*4+2] = bf2f(xv[2]);
        xs[wv][lane*4+3] = bf2f(xv[3]);
    }
    __syncthreads();
    int c = (lane < 40) ? lane : 39;
    float acc = 0.f;
    #pragma unroll 8
    for (int k = 0; k < 64; ++k)
        acc = fmaf(xs[wv][k], w2s[k*40 + c], acc);
    float s = (lane < 40) ? acc * aS2[lane] : 0.f;
    float d = (lane < 40) ? acc * aD2[lane] : 0.f;
    #pragma unroll
    for (int off = 32; off > 0; off >>= 1){ s += __shfl_down(s, off, 64); d += __shfl_down(d, off, 64); }
    if (valid){
        if (lane < 40) h2b[(size_t)n*40 + lane] = f2bf(acc);
        if (lane == 0){ as2[n] = s; ad2[n] = d; }
    }
}

// ---------- layer-2 aggregate: 16-lane group/dst, lanes r<10 own 4 features ----------
__global__ __launch_bounds__(256) void agg2(const short* __restrict__ h2b,
        const float* __restrict__ as2, const float* __restrict__ ad2,
        const int* __restrict__ offs, const int* __restrict__ deg, const int* __restrict__ csr,
        const float* __restrict__ b2, float* __restrict__ out, int N){
    int w = blockIdx.x*16 + (threadIdx.x >> 4);
    if (w < N){
        int r = threadIdx.x & 15;
        bool pay = r < 10;
        int f0 = pay ? r*4 : 0;                              // clamp: in-bounds loads
        int s0 = offs[w], d = deg[w];
        float ad = ad2[w];
        float l = 0.f;
        float4v acc = {};
        int i = 0;
        for (; i + 4 <= d; i += 4){
            int sa = csr[s0+i], sb = csr[s0+i+1], sc = csr[s0+i+2], sd = csr[s0+i+3];
            float ea = as2[sa], eb = as2[sb], ec = as2[sc], ed = as2[sd];
            short4v va = *(const short4v*)&h2b[(size_t)sa*40 + f0];
            short4v vb = *(const short4v*)&h2b[(size_t)sb*40 + f0];
            short4v vc = *(const short4v*)&h2b[(size_t)sc*40 + f0];
            short4v vd = *(const short4v*)&h2b[(size_t)sd*40 + f0];
            ea += ad; ea = (ea > 0.f) ? ea : NEG_SLOPE*ea; float pa = __expf(ea);
            eb += ad; eb = (eb > 0.f) ? eb : NEG_SLOPE*eb; float pb = __expf(eb);
            ec += ad; ec = (ec > 0.f) ? ec : NEG_SLOPE*ec; float pc = __expf(ec);
            ed += ad; ed = (ed > 0.f) ? ed : NEG_SLOPE*ed; float pd = __expf(ed);
            l += (pa + pb) + (pc + pd);
            #pragma unroll
            for (int j = 0; j < 4; ++j){
                acc[j] = fmaf(pa, bf2f(va[j]), acc[j]);
                acc[j] = fmaf(pb, bf2f(vb[j]), acc[j]);
                acc[j] = fmaf(pc, bf2f(vc[j]), acc[j]);
                acc[j] = fmaf(pd, bf2f(vd[j]), acc[j]);
            }
        }
        for (; i < d; ++i){
            int s = csr[s0 + i];
            float e = as2[s] + ad;
            e = (e > 0.f) ? e : NEG_SLOPE*e;
            float p = __expf(e);
            l += p;
            short4v v = *(const short4v*)&h2b[(size_t)s*40 + f0];
            #pragma unroll
            for (int j = 0; j < 4; ++j)
                acc[j] = fmaf(p, bf2f(v[j]), acc[j]);
        }
        if (pay){
            float4 o;
            o.x = acc[0]/(l + 1e-16f) + b2[f0+0];
            o.y = acc[1]/(l + 1e-16f) + b2[f0+1];
            o.z = acc[2]/(l + 1e-16f) + b2[f0+2];
            o.w = acc[3]/(l + 1e-16f) + b2[f0+3];
            *(float4*)&out[(size_t)w*40 + f0] = o;
        }
    }
}

extern "C" void kernel_launch(void* const* d_in, const int* in_sizes, int n_in,
                              void* d_out, int out_size, void* d_ws, size_t ws_size,
                              hipStream_t stream) {
    const float* x    = (const float*)d_in[0];
    const int*   ei   = (const int*)d_in[1];
    const float* W1   = (const float*)d_in[2];
    const float* aS1  = (const float*)d_in[3];
    const float* aD1  = (const float*)d_in[4];
    const float* b1   = (const float*)d_in[5];
    const float* W2   = (const float*)d_in[6];
    const float* aS2  = (const float*)d_in[7];
    const float* aD2  = (const float*)d_in[8];
    const float* b2   = (const float*)d_in[9];
    float* out = (float*)d_out;

    const int N    = in_sizes[0] / 512;
    const int E    = in_sizes[1] / 2;
    const int Etot = E + N;
    const int K    = (N + 255) >> 8;          // buckets of 256 dst nodes
    const int nAB  = (Etot + 8191) / 8192;    // edge chunks for hist/place

    // workspace carve (256B aligned), ~68 MB total
    char* p = (char*)d_ws;
    auto carve = [&](size_t bytes)->char*{ char* q = p; p += ((bytes + 255) & ~(size_t)255); return q; };
    short* h1b   = (short*)carve((size_t)N*64*2);
    short* x1b   = (short*)carve((size_t)N*64*2);
    short* h2b   = (short*)carve((size_t)N*40*2);
    float* as1   = (float*)carve((size_t)N*8*4);
    float* ad1   = (float*)carve((size_t)N*8*4);
    float* as2   = (float*)carve((size_t)N*4);
    float* ad2   = (float*)carve((size_t)N*4);
    int*   deg   = (int*)carve((size_t)N*4);
    int*   offs  = (int*)carve((size_t)N*4);
    int*   bhist = (int*)carve((size_t)(K+1)*4);
    int*   bbase = (int*)carve((size_t)(K+1)*4);
    int*   bcursor=(int*)carve((size_t)(K+1)*4);
    int*   flag  = (int*)carve(256);
    short* Bhi   = (short*)carve(64*512*2);
    short* Blo   = (short*)carve(64*512*2);
    int*   csr   = (int*)carve((size_t)Etot*4);
    int*   staging = (int*)carve((size_t)Etot*4);

    hipMemsetAsync(bhist, 0, (size_t)K*4, stream);

    detect_i64<<<1, 1024, 0, stream>>>(ei, flag);
    pack_w1<<<(64*512 + 255)/256, 256, 0, stream>>>(W1, Bhi, Blo);

    // CSR build: bucket sort, no per-edge global atomics, no random scatter.
    bucket_hist <<<nAB, 256, (size_t)K*4,   stream>>>(ei, flag, bhist, E, Etot, K);
    bucket_scan <<<1, 1024, 0,              stream>>>(bhist, bbase, bcursor, K);
    bucket_place<<<nAB, 256, (size_t)2*K*4, stream>>>(ei, flag, bcursor, staging, E, Etot, K);
    bucket_csr  <<<K, 256, 0,               stream>>>(staging, bbase, offs, deg, csr, N, K);

    gemm1 <<<(N + 63)/64, 256, 0, stream>>>(x, Bhi, Blo, aS1, aD1, h1b, as1, ad1, N);

    agg1  <<<(N + 15)/16, 256, 0, stream>>>(h1b, as1, ad1, offs, deg, csr, b1, x1b, N);
    gemm2a<<<(N + 3)/4,   256, 0, stream>>>(x1b, W2, aS2, aD2, h2b, as2, ad2, N);
    agg2  <<<(N + 15)/16, 256, 0, stream>>>(h2b, as2, ad2, offs, deg, csr, b2, out, N);
}

// Round 7
// 660.395 us; speedup vs baseline: 1.2550x; 1.0546x over previous
//
#include <hip/hip_runtime.h>
#include <hip/hip_bf16.h>

// GAT 2-layer, MI355X. fp32 inputs. Split-bf16 MFMA GEMM1 (exact logit path),
// CSR-by-dst aggregation.
// R10: gemm1 still latency-bound (133us, MfmaUtil 5.6%, VALUBusy 8.1%,
// VGPR=52): 16 B-loads/K-step consumed immediately (no reg dbuf at 52 VGPR),
// and x-prefetch drained early because vmcnt retires in issue order (B waits
// drain older x loads). Rebuilt: BM=128 (4 waves x 32 rows, 2 m-tiles/wave,
// B traffic/row halved), BK=32, LDS [2][128][36] dbuf (36.8KB < 64KB cap,
// pad 36 => 2-way free ds_read_b128), launch_bounds(256,3) -> 3 blocks/CU
// (grid 782 = one generation), per-step: 8 B-loads hoisted+issued FIRST, x
// t+1 loads second (stay outstanding across whole iter), ds/split/MFMA after.
// Same MFMA order per acc => bit-identical. One extra barrier before C-park
// (park spans both A buffers). agg 16-lane groups from R7/R9; fragment-order
// B pack from R6; bucket CSR from R4.

typedef __attribute__((ext_vector_type(8))) short short8;
typedef __attribute__((ext_vector_type(4))) short short4v;
typedef __attribute__((ext_vector_type(4))) float float4v;

#define NEG_SLOPE 0.2f

static __device__ __forceinline__ short f2bf(float v){
    union { float f; unsigned u; } x; x.f = v;
    unsigned r = x.u + 0x7fffu + ((x.u >> 16) & 1u);   // RNE
    return (short)(r >> 16);
}
static __device__ __forceinline__ float bf2f(short s){
    union { unsigned u; float f; } x; x.u = ((unsigned)(unsigned short)s) << 16;
    return x.f;
}

// ---------- W1 pack: fp32 -> bf16 hi/lo in MFMA-fragment order ----------
// Fragment (kb,ct,lane) at short8 index (kb*4+ct)*64+lane, lane=q*16+m:
// element j maps to W1[k][n], n=ct*16+m, k=kb*32+q*8+j (kb=0..15).
__global__ void pack_w1(const float* __restrict__ W1, short* __restrict__ Bhi, short* __restrict__ Blo){
    int idx = blockIdx.x*blockDim.x + threadIdx.x;     // 64*512
    if (idx >= 64*512) return;
    int j    = idx & 7;
    int lane = (idx >> 3) & 63;
    int ct   = (idx >> 9) & 3;
    int kb   = idx >> 11;                              // 0..15
    int m = lane & 15, q = lane >> 4;
    int n = ct*16 + m;
    int k = kb*32 + q*8 + j;
    float w = W1[k*64 + n];
    short h = f2bf(w);
    Bhi[idx] = h;
    Blo[idx] = f2bf(w - bf2f(h));
}

// ---------- edge_index int64-layout probe: all odd words zero => int64 ----------
__global__ void detect_i64(const int* __restrict__ ei, int* __restrict__ flag){
    __shared__ int any;
    if (threadIdx.x == 0) any = 0;
    __syncthreads();
    if (ei[2*threadIdx.x + 1] != 0) atomicAdd(&any, 1);
    __syncthreads();
    if (threadIdx.x == 0) flag[0] = (any == 0) ? 1 : 0;   // 1 => int64 layout
}

// ---------- layer-1 GEMM: h1 = x @ W1, split-bf16 MFMA; fused alpha1 ----------
// 256 thr = 4 waves x 32 rows (2 m-tiles). BK=32, dbuf LDS [2][128][36].
__global__ __launch_bounds__(256, 3) void gemm1(const float* __restrict__ x,
        const short* __restrict__ Bhi, const short* __restrict__ Blo,
        const float* __restrict__ aS1, const float* __restrict__ aD1,
        short* __restrict__ h1b, float* __restrict__ as1, float* __restrict__ ad1, int N){
    __shared__ __align__(16) float As[2][128][36];
    int tid = threadIdx.x;
    int wave = tid >> 6, lane = tid & 63;
    int m = lane & 15, q = lane >> 4;
    int rowbase = blockIdx.x*128;

    const short8* Bh = (const short8*)Bhi;
    const short8* Bl = (const short8*)Blo;

    // staging map: float4 slot s = i*256+tid; row=s>>3 (0..127), c4=s&7
    int srow[4]; int scol[4];
    #pragma unroll
    for (int i = 0; i < 4; ++i){
        int s = i*256 + tid;
        int r = rowbase + (s >> 3);
        srow[i] = (r < N) ? r : (N-1);
        scol[i] = (s & 7) * 4;
    }

    float4 reg[4];
    #pragma unroll
    for (int i = 0; i < 4; ++i)
        reg[i] = *(const float4*)(x + (size_t)srow[i]*512 + scol[i]);
    #pragma unroll
    for (int i = 0; i < 4; ++i){
        int s = i*256 + tid;
        *(float4*)&As[0][s >> 3][scol[i]] = reg[i];
    }
    __syncthreads();

    float4v acc[2][4] = {};
    for (int t = 0; t < 16; ++t){
        int cur = t & 1, nxt = cur ^ 1;
        // (1) B fragments for this K-step: issued first => MFMA's vmcnt wait
        //     does NOT drain the younger x-prefetch loads.
        int fb = t*256 + lane;
        short8 bhi0 = Bh[fb];        short8 blo0 = Bl[fb];
        short8 bhi1 = Bh[fb + 64];   short8 blo1 = Bl[fb + 64];
        short8 bhi2 = Bh[fb + 128];  short8 blo2 = Bl[fb + 128];
        short8 bhi3 = Bh[fb + 192];  short8 blo3 = Bl[fb + 192];
        // (2) x prefetch for t+1: outstanding until ds_write at iter end.
        if (t < 15){
            #pragma unroll
            for (int i = 0; i < 4; ++i)
                reg[i] = *(const float4*)(x + (size_t)srow[i]*512 + (t+1)*32 + scol[i]);
        }
        // (3) A fragments from LDS + split, both m-tiles.
        short8 ahi[2], alo[2];
        #pragma unroll
        for (int mt = 0; mt < 2; ++mt){
            const float* arow = &As[cur][wave*32 + mt*16 + m][0];
            float v[8];
            *(float4*)&v[0] = *(const float4*)(arow + q*8);
            *(float4*)&v[4] = *(const float4*)(arow + q*8 + 4);
            #pragma unroll
            for (int j = 0; j < 8; ++j){
                union { float f; unsigned u; } tt; tt.f = v[j];
                ahi[mt][j] = (short)(tt.u >> 16);              // truncation split
                union { unsigned u; float f; } th; th.u = tt.u & 0xffff0000u;
                alo[mt][j] = f2bf(v[j] - th.f);
            }
        }
        // (4) MFMA: per acc identical order (kb asc; hi*hi, hi*lo, lo*hi).
        #pragma unroll
        for (int mt = 0; mt < 2; ++mt){
            acc[mt][0] = __builtin_amdgcn_mfma_f32_16x16x32_bf16(ahi[mt], bhi0, acc[mt][0], 0, 0, 0);
            acc[mt][0] = __builtin_amdgcn_mfma_f32_16x16x32_bf16(ahi[mt], blo0, acc[mt][0], 0, 0, 0);
            acc[mt][0] = __builtin_amdgcn_mfma_f32_16x16x32_bf16(alo[mt], bhi0, acc[mt][0], 0, 0, 0);
            acc[mt][1] = __builtin_amdgcn_mfma_f32_16x16x32_bf16(ahi[mt], bhi1, acc[mt][1], 0, 0, 0);
            acc[mt][1] = __builtin_amdgcn_mfma_f32_16x16x32_bf16(ahi[mt], blo1, acc[mt][1], 0, 0, 0);
            acc[mt][1] = __builtin_amdgcn_mfma_f32_16x16x32_bf16(alo[mt], bhi1, acc[mt][1], 0, 0, 0);
            acc[mt][2] = __builtin_amdgcn_mfma_f32_16x16x32_bf16(ahi[mt], bhi2, acc[mt][2], 0, 0, 0);
            acc[mt][2] = __builtin_amdgcn_mfma_f32_16x16x32_bf16(ahi[mt], blo2, acc[mt][2], 0, 0, 0);
            acc[mt][2] = __builtin_amdgcn_mfma_f32_16x16x32_bf16(alo[mt], bhi2, acc[mt][2], 0, 0, 0);
            acc[mt][3] = __builtin_amdgcn_mfma_f32_16x16x32_bf16(ahi[mt], bhi3, acc[mt][3], 0, 0, 0);
            acc[mt][3] = __builtin_amdgcn_mfma_f32_16x16x32_bf16(ahi[mt], blo3, acc[mt][3], 0, 0, 0);
            acc[mt][3] = __builtin_amdgcn_mfma_f32_16x16x32_bf16(alo[mt], bhi3, acc[mt][3], 0, 0, 0);
        }
        // (5) stage t+1 into nxt buffer.
        if (t < 15){
            #pragma unroll
            for (int i = 0; i < 4; ++i){
                int s = i*256 + tid;
                *(float4*)&As[nxt][s >> 3][scol[i]] = reg[i];
            }
            __syncthreads();
        }
    }

    // barrier: park region (pitch-68 flat) spans both A buffers.
    __syncthreads();
    float* cw = &As[0][0][0] + wave*(32*68);
    #pragma unroll
    for (int mt = 0; mt < 2; ++mt)
        #pragma unroll
        for (int ct = 0; ct < 4; ++ct)
            #pragma unroll
            for (int r = 0; r < 4; ++r)
                cw[(mt*16 + q*4 + r)*68 + ct*16 + m] = acc[mt][ct][r];  // C/D: col=lane&15, row=quad*4+reg

    int row_l = lane >> 2;
    int cseg  = (lane & 3) * 16;
    int h0 = (lane & 3) * 2;
    #pragma unroll
    for (int p = 0; p < 2; ++p){
        int lr = p*16 + row_l;
        int gr = rowbase + wave*32 + lr;
        float vals[16];
        #pragma unroll
        for (int i = 0; i < 4; ++i)
            *(float4*)&vals[i*4] = *(const float4*)&cw[lr*68 + cseg + i*4];
        if (gr < N){
            short8 o0, o1;
            #pragma unroll
            for (int j = 0; j < 8; ++j){ o0[j] = f2bf(vals[j]); o1[j] = f2bf(vals[8+j]); }
            *(short8*)&h1b[(size_t)gr*64 + cseg]     = o0;
            *(short8*)&h1b[(size_t)gr*64 + cseg + 8] = o1;
            float s0 = 0.f, d0 = 0.f, s1 = 0.f, d1 = 0.f;
            #pragma unroll
            for (int c = 0; c < 8; ++c){
                s0 = fmaf(vals[c],   aS1[h0*8+c],     s0);
                d0 = fmaf(vals[c],   aD1[h0*8+c],     d0);
                s1 = fmaf(vals[8+c], aS1[(h0+1)*8+c], s1);
                d1 = fmaf(vals[8+c], aD1[(h0+1)*8+c], d1);
            }
            float2 sv; sv.x = s0; sv.y = s1;
            float2 dv; dv.x = d0; dv.y = d1;
            *(float2*)&as1[(size_t)gr*8 + h0] = sv;
            *(float2*)&ad1[(size_t)gr*8 + h0] = dv;
        }
    }
}

// ---------- CSR build via bucket sort (bucket = dst>>8, 256 nodes/bucket) ----------
__global__ __launch_bounds__(256) void bucket_hist(const int* __restrict__ ei,
        const int* __restrict__ flag, int* __restrict__ bhist, int E, int Etot, int K){
    extern __shared__ int hist[];                          // K ints
    for (int i = threadIdx.x; i < K; i += 256) hist[i] = 0;
    __syncthreads();
    int f = flag[0];
    int e0 = blockIdx.x*8192, e1 = min(e0 + 8192, Etot);
    for (int e = e0 + threadIdx.x; e < e1; e += 256){
        int dst = (e < E) ? ei[((size_t)(E + e)) << f] : (e - E);
        atomicAdd(&hist[dst >> 8], 1);
    }
    __syncthreads();
    for (int i = threadIdx.x; i < K; i += 256)
        if (hist[i]) atomicAdd(&bhist[i], hist[i]);
}

__global__ __launch_bounds__(1024) void bucket_scan(const int* __restrict__ bhist,
        int* __restrict__ bbase, int* __restrict__ bcursor, int K){
    __shared__ int s[1024];
    int t = threadIdx.x;
    int v = (t < K) ? bhist[t] : 0;
    s[t] = v; __syncthreads();
    for (int off = 1; off < 1024; off <<= 1){
        int x = (t >= off) ? s[t-off] : 0;
        __syncthreads();
        s[t] += x;
        __syncthreads();
    }
    if (t < K){ int excl = s[t] - v; bbase[t] = excl; bcursor[t] = excl; }
    if (t == K) bbase[K] = s[t];                           // total = Etot
}

__global__ __launch_bounds__(256) void bucket_place(const int* __restrict__ ei,
        const int* __restrict__ flag, int* __restrict__ bcursor,
        int* __restrict__ staging, int E, int Etot, int K){
    extern __shared__ int sm[];                            // hist[K] + base[K]
    int* hist = sm;
    int* base = sm + K;
    for (int i = threadIdx.x; i < K; i += 256) hist[i] = 0;
    __syncthreads();
    int f = flag[0];
    int e0 = blockIdx.x*8192, e1 = min(e0 + 8192, Etot);
    for (int e = e0 + threadIdx.x; e < e1; e += 256){
        int dst = (e < E) ? ei[((size_t)(E + e)) << f] : (e - E);
        atomicAdd(&hist[dst >> 8], 1);
    }
    __syncthreads();
    for (int i = threadIdx.x; i < K; i += 256){
        int c = hist[i];
        base[i] = c ? atomicAdd(&bcursor[i], c) : 0;
        hist[i] = 0;                                       // reuse as running cursor
    }
    __syncthreads();
    for (int e = e0 + threadIdx.x; e < e1; e += 256){
        int src, dst;
        if (e < E){ src = ei[((size_t)e) << f]; dst = ei[((size_t)(E + e)) << f]; }
        else      { src = dst = e - E; }
        int k = dst >> 8;
        int r = atomicAdd(&hist[k], 1);
        staging[base[k] + r] = (src << 8) | (dst & 255);   // src < 2^24 assumed
    }
}

__global__ __launch_bounds__(256) void bucket_csr(const int* __restrict__ staging,
        const int* __restrict__ bbase, int* __restrict__ offs, int* __restrict__ deg,
        int* __restrict__ csr, int N, int K){
    __shared__ int dcnt[256], sc[256], cur[256];
    int k = blockIdx.x, t = threadIdx.x;
    dcnt[t] = 0;
    __syncthreads();
    int s0 = bbase[k], s1 = bbase[k+1];
    for (int i = s0 + t; i < s1; i += 256)
        atomicAdd(&dcnt[staging[i] & 255], 1);
    __syncthreads();
    int v = dcnt[t];
    sc[t] = v; __syncthreads();
    for (int off = 1; off < 256; off <<= 1){
        int x = (t >= off) ? sc[t-off] : 0;
        __syncthreads();
        sc[t] += x;
        __syncthreads();
    }
    int excl = sc[t] - v;
    int node = (k << 8) + t;
    if (node < N){ offs[node] = s0 + excl; deg[node] = v; }
    cur[t] = excl;
    __syncthreads();
    for (int i = s0 + t; i < s1; i += 256){
        int ent = staging[i];
        int p = atomicAdd(&cur[ent & 255], 1);
        csr[s0 + p] = ent >> 8;
    }
}

// ---------- layer-1 aggregate: 16-lane group/dst, lane owns 4 features ----------
__global__ __launch_bounds__(256) void agg1(const short* __restrict__ h1b,
        const float* __restrict__ as1, const float* __restrict__ ad1,
        const int* __restrict__ offs, const int* __restrict__ deg, const int* __restrict__ csr,
        const float* __restrict__ b1, short* __restrict__ x1b, int N){
    int w = blockIdx.x*16 + (threadIdx.x >> 4);
    if (w < N){
        int r = threadIdx.x & 15;
        int h = r >> 1;                  // features r*4..r*4+3 all in head r>>1
        int f0 = r*4;
        int s0 = offs[w], d = deg[w];
        float ad = ad1[w*8 + h];
        float l = 0.f;
        float4v acc = {};
        int i = 0;
        for (; i + 4 <= d; i += 4){
            int sa = csr[s0+i], sb = csr[s0+i+1], sc = csr[s0+i+2], sd = csr[s0+i+3];
            float ea = as1[sa*8+h], eb = as1[sb*8+h], ec = as1[sc*8+h], ed = as1[sd*8+h];
            short4v va = *(const short4v*)&h1b[(size_t)sa*64 + f0];
            short4v vb = *(const short4v*)&h1b[(size_t)sb*64 + f0];
            short4v vc = *(const short4v*)&h1b[(size_t)sc*64 + f0];
            short4v vd = *(const short4v*)&h1b[(size_t)sd*64 + f0];
            ea += ad; ea = (ea > 0.f) ? ea : NEG_SLOPE*ea; float pa = __expf(ea);
            eb += ad; eb = (eb > 0.f) ? eb : NEG_SLOPE*eb; float pb = __expf(eb);
            ec += ad; ec = (ec > 0.f) ? ec : NEG_SLOPE*ec; float pc = __expf(ec);
            ed += ad; ed = (ed > 0.f) ? ed : NEG_SLOPE*ed; float pd = __expf(ed);
            l += (pa + pb) + (pc + pd);
            #pragma unroll
            for (int j = 0; j < 4; ++j){
                acc[j] = fmaf(pa, bf2f(va[j]), acc[j]);
                acc[j] = fmaf(pb, bf2f(vb[j]), acc[j]);
                acc[j] = fmaf(pc, bf2f(vc[j]), acc[j]);
                acc[j] = fmaf(pd, bf2f(vd[j]), acc[j]);
            }
        }
        for (; i < d; ++i){
            int s = csr[s0 + i];
            float e = as1[s*8 + h] + ad;
            e = (e > 0.f) ? e : NEG_SLOPE*e;
            float p = __expf(e);
            l += p;
            short4v v = *(const short4v*)&h1b[(size_t)s*64 + f0];
            #pragma unroll
            for (int j = 0; j < 4; ++j)
                acc[j] = fmaf(p, bf2f(v[j]), acc[j]);
        }
        short4v o;
        #pragma unroll
        for (int j = 0; j < 4; ++j){
            float ov = acc[j]/(l + 1e-16f) + b1[f0+j];
            ov = (ov > 0.f) ? ov : (__expf(ov) - 1.f);       // ELU
            o[j] = f2bf(ov);
        }
        *(short4v*)&x1b[(size_t)w*64 + f0] = o;
    }
}

// ---------- layer-2 GEMM fused with alpha2: wave/node; fp32 logit path ----------
__global__ __launch_bounds__(256) void gemm2a(const short* __restrict__ x1b,
        const float* __restrict__ W2, const float* __restrict__ aS2, const float* __restrict__ aD2,
        short* __restrict__ h2b, float* __restrict__ as2, float* __restrict__ ad2, int N){
    __shared__ float w2s[64*40];                            // 10,240 B
    __shared__ float xs[4][64];
    int tid = threadIdx.x;
    for (int i = tid; i < 64*40; i += 256) w2s[i] = W2[i];  // W2 [64][40] row-major
    int wv = tid >> 6, lane = tid & 63;
    int n = blockIdx.x*4 + wv;
    bool valid = n < N;
    if (valid && lane < 16){
        short4v xv = *(const short4v*)&x1b[(size_t)n*64 + lane*4];
        xs[wv][lane*4+0] = bf2f(xv[0]);
        xs[wv][lane*4+1] = bf2f(xv[1]);
        xs[wv][lane*4+2] = bf2f(xv[2]);
        xs[wv][lane*4+3] = bf2f(xv[3]);
    }
    __syncthreads();
    int c = (lane < 40) ? lane : 39;
    float acc = 0.f;
    #pragma unroll 8
    for (int k = 0; k < 64; ++k)
        acc = fmaf(xs[wv][k], w2s[k*40 + c], acc);
    float s = (lane < 40) ? acc * aS2[lane] : 0.f;
    float d = (lane < 40) ? acc * aD2[lane] : 0.f;
    #pragma unroll
    for (int off = 32; off > 0; off >>= 1){ s += __shfl_down(s, off, 64); d += __shfl_down(d, off, 64); }
    if (valid){
        if (lane < 40) h2b[(size_t)n*40 + lane] = f2bf(acc);
        if (lane == 0){ as2[n] = s; ad2[n] = d; }
    }
}

// ---------- layer-2 aggregate: 16-lane group/dst, lanes r<10 own 4 features ----------
__global__ __launch_bounds__(256) void agg2(const short* __restrict__ h2b,
        const float* __restrict__ as2, const float* __restrict__ ad2,
        const int* __restrict__ offs, const int* __restrict__ deg, const int* __restrict__ csr,
        const float* __restrict__ b2, float* __restrict__ out, int N){
    int w = blockIdx.x*16 + (threadIdx.x >> 4);
    if (w < N){
        int r = threadIdx.x & 15;
        bool pay = r < 10;
        int f0 = pay ? r*4 : 0;                              // clamp: in-bounds loads
        int s0 = offs[w], d = deg[w];
        float ad = ad2[w];
        float l = 0.f;
        float4v acc = {};
        int i = 0;
        for (; i + 4 <= d; i += 4){
            int sa = csr[s0+i], sb = csr[s0+i+1], sc = csr[s0+i+2], sd = csr[s0+i+3];
            float ea = as2[sa], eb = as2[sb], ec = as2[sc], ed = as2[sd];
            short4v va = *(const short4v*)&h2b[(size_t)sa*40 + f0];
            short4v vb = *(const short4v*)&h2b[(size_t)sb*40 + f0];
            short4v vc = *(const short4v*)&h2b[(size_t)sc*40 + f0];
            short4v vd = *(const short4v*)&h2b[(size_t)sd*40 + f0];
            ea += ad; ea = (ea > 0.f) ? ea : NEG_SLOPE*ea; float pa = __expf(ea);
            eb += ad; eb = (eb > 0.f) ? eb : NEG_SLOPE*eb; float pb = __expf(eb);
            ec += ad; ec = (ec > 0.f) ? ec : NEG_SLOPE*ec; float pc = __expf(ec);
            ed += ad; ed = (ed > 0.f) ? ed : NEG_SLOPE*ed; float pd = __expf(ed);
            l += (pa + pb) + (pc + pd);
            #pragma unroll
            for (int j = 0; j < 4; ++j){
                acc[j] = fmaf(pa, bf2f(va[j]), acc[j]);
                acc[j] = fmaf(pb, bf2f(vb[j]), acc[j]);
                acc[j] = fmaf(pc, bf2f(vc[j]), acc[j]);
                acc[j] = fmaf(pd, bf2f(vd[j]), acc[j]);
            }
        }
        for (; i < d; ++i){
            int s = csr[s0 + i];
            float e = as2[s] + ad;
            e = (e > 0.f) ? e : NEG_SLOPE*e;
            float p = __expf(e);
            l += p;
            short4v v = *(const short4v*)&h2b[(size_t)s*40 + f0];
            #pragma unroll
            for (int j = 0; j < 4; ++j)
                acc[j] = fmaf(p, bf2f(v[j]), acc[j]);
        }
        if (pay){
            float4 o;
            o.x = acc[0]/(l + 1e-16f) + b2[f0+0];
            o.y = acc[1]/(l + 1e-16f) + b2[f0+1];
            o.z = acc[2]/(l + 1e-16f) + b2[f0+2];
            o.w = acc[3]/(l + 1e-16f) + b2[f0+3];
            *(float4*)&out[(size_t)w*40 + f0] = o;
        }
    }
}

extern "C" void kernel_launch(void* const* d_in, const int* in_sizes, int n_in,
                              void* d_out, int out_size, void* d_ws, size_t ws_size,
                              hipStream_t stream) {
    const float* x    = (const float*)d_in[0];
    const int*   ei   = (const int*)d_in[1];
    const float* W1   = (const float*)d_in[2];
    const float* aS1  = (const float*)d_in[3];
    const float* aD1  = (const float*)d_in[4];
    const float* b1   = (const float*)d_in[5];
    const float* W2   = (const float*)d_in[6];
    const float* aS2  = (const float*)d_in[7];
    const float* aD2  = (const float*)d_in[8];
    const float* b2   = (const float*)d_in[9];
    float* out = (float*)d_out;

    const int N    = in_sizes[0] / 512;
    const int E    = in_sizes[1] / 2;
    const int Etot = E + N;
    const int K    = (N + 255) >> 8;          // buckets of 256 dst nodes
    const int nAB  = (Etot + 8191) / 8192;    // edge chunks for hist/place

    // workspace carve (256B aligned), ~68 MB total
    char* p = (char*)d_ws;
    auto carve = [&](size_t bytes)->char*{ char* q = p; p += ((bytes + 255) & ~(size_t)255); return q; };
    short* h1b   = (short*)carve((size_t)N*64*2);
    short* x1b   = (short*)carve((size_t)N*64*2);
    short* h2b   = (short*)carve((size_t)N*40*2);
    float* as1   = (float*)carve((size_t)N*8*4);
    float* ad1   = (float*)carve((size_t)N*8*4);
    float* as2   = (float*)carve((size_t)N*4);
    float* ad2   = (float*)carve((size_t)N*4);
    int*   deg   = (int*)carve((size_t)N*4);
    int*   offs  = (int*)carve((size_t)N*4);
    int*   bhist = (int*)carve((size_t)(K+1)*4);
    int*   bbase = (int*)carve((size_t)(K+1)*4);
    int*   bcursor=(int*)carve((size_t)(K+1)*4);
    int*   flag  = (int*)carve(256);
    short* Bhi   = (short*)carve(64*512*2);
    short* Blo   = (short*)carve(64*512*2);
    int*   csr   = (int*)carve((size_t)Etot*4);
    int*   staging = (int*)carve((size_t)Etot*4);

    hipMemsetAsync(bhist, 0, (size_t)K*4, stream);

    detect_i64<<<1, 1024, 0, stream>>>(ei, flag);
    pack_w1<<<(64*512 + 255)/256, 256, 0, stream>>>(W1, Bhi, Blo);

    // CSR build: bucket sort, no per-edge global atomics, no random scatter.
    bucket_hist <<<nAB, 256, (size_t)K*4,   stream>>>(ei, flag, bhist, E, Etot, K);
    bucket_scan <<<1, 1024, 0,              stream>>>(bhist, bbase, bcursor, K);
    bucket_place<<<nAB, 256, (size_t)2*K*4, stream>>>(ei, flag, bcursor, staging, E, Etot, K);
    bucket_csr  <<<K, 256, 0,               stream>>>(staging, bbase, offs, deg, csr, N, K);

    gemm1 <<<(N + 127)/128, 256, 0, stream>>>(x, Bhi, Blo, aS1, aD1, h1b, as1, ad1, N);

    agg1  <<<(N + 15)/16, 256, 0, stream>>>(h1b, as1, ad1, offs, deg, csr, b1, x1b, N);
    gemm2a<<<(N + 3)/4,   256, 0, stream>>>(x1b, W2, aS2, aD2, h2b, as2, ad2, N);
    agg2  <<<(N + 15)/16, 256, 0, stream>>>(h2b, as2, ad2, offs, deg, csr, b2, out, N);
}